// Round 5
// baseline (395.453 us; speedup 1.0000x reference)
//
#include <hip/hip_runtime.h>
#include <hip/hip_bf16.h>

// Problem constants
#define S_LEN   2048
#define HID     2560
#define NH      32
#define NKV     8
#define HD      128
#define QDIM    (NH*HD)    // 4096
#define KVDIM   (NKV*HD)   // 1024

typedef __attribute__((ext_vector_type(8))) short short8;   // 8 bf16 (4 VGPRs)
typedef __attribute__((ext_vector_type(4))) float f32x4;    // MFMA C/D frag

__device__ __forceinline__ unsigned short f2bf(float f) {
    unsigned u = __float_as_uint(f);
    u += 0x7fffu + ((u >> 16) & 1u);        // round-to-nearest-even
    return (unsigned short)(u >> 16);
}
__device__ __forceinline__ float bf2f(unsigned short s) {
    return __uint_as_float(((unsigned)s) << 16);
}
// packed f32x2 -> bf16x2 (v_cvt_pk_bf16_f32 on gfx950)
__device__ __forceinline__ unsigned pk2bf(float a, float b) {
    __hip_bfloat162 h = __float22bfloat162_rn(make_float2(a, b));
    union { __hip_bfloat162 h; unsigned u; } c; c.h = h; return c.u;
}
__device__ __forceinline__ void gload16(const void* g, void* l) {
    __builtin_amdgcn_global_load_lds(
        (const __attribute__((address_space(1))) unsigned int*)g,
        (__attribute__((address_space(3))) unsigned int*)l, 16, 0, 0);
}

// ---------------------------------------------------------------------------
// Fused fp32 -> bf16 converts: hs, Wq, Wk, Wv in one segmented launch.
// ---------------------------------------------------------------------------
#define N4_HS  (S_LEN*HID/4)        // 1310720
#define N4_WQ  (QDIM*HID/4)         // 2621440
#define N4_WKV (KVDIM*HID/4)        // 655360
__global__ __launch_bounds__(256) void cvt4(
    const float* __restrict__ hs, const float* __restrict__ Wq,
    const float* __restrict__ Wk, const float* __restrict__ Wv,
    unsigned short* __restrict__ hsB, unsigned short* __restrict__ WqB,
    unsigned short* __restrict__ WkB, unsigned short* __restrict__ WvB)
{
    int i = blockIdx.x * 256 + threadIdx.x;
    const float* s; unsigned short* d;
    if (i < N4_HS)                          { s = hs; d = hsB; }
    else if (i < N4_HS + N4_WQ)             { i -= N4_HS; s = Wq; d = WqB; }
    else if (i < N4_HS + N4_WQ + N4_WKV)    { i -= N4_HS + N4_WQ; s = Wk; d = WkB; }
    else                                    { i -= N4_HS + N4_WQ + N4_WKV; s = Wv; d = WvB; }
    float4 v = ((const float4*)s)[i];
    uint2 o;
    o.x = pk2bf(v.x, v.y); o.y = pk2bf(v.z, v.w);
    ((uint2*)d)[i] = o;
}

__global__ __launch_bounds__(256) void cvt_f32_bf16(
    const float* __restrict__ s, unsigned short* __restrict__ d, int n4)
{
    int i = blockIdx.x * 256 + threadIdx.x;
    if (i >= n4) return;
    float4 v = ((const float4*)s)[i];
    uint2 o;
    o.x = pk2bf(v.x, v.y); o.y = pk2bf(v.z, v.w);
    ((uint2*)d)[i] = o;
}

// ---------------------------------------------------------------------------
// BK=64 GEMM core (128x128): 256 threads, 4 waves (2x2 of 64x64).
// XOR swizzle on the GLOBAL chunk; fragment reads apply the same XOR.
// (Proven 76 µs structure; 256x256 8-phase rewrites measured 86-100 µs.)
// ---------------------------------------------------------------------------
struct GemmRegs {
    f32x4 acc[4][4];
};
__device__ __forceinline__ void gemm_core(
    const unsigned short* A, const unsigned short* B, int Kd,
    unsigned short* As, unsigned short* Bs, GemmRegs& R,
    int rowA0, int rowB0, int tid)
{
    const int lane = tid & 63;
    const int l15 = lane & 15, l4 = lane >> 4;
    const int w = tid >> 6;
    const int wr = (w >> 1) * 64, wc = (w & 1) * 64;
    const int sw = l15 & 7;                 // read-side XOR swizzle

#pragma unroll
    for (int i = 0; i < 4; i++)
#pragma unroll
        for (int j = 0; j < 4; j++)
            R.acc[i][j] = (f32x4){0.f, 0.f, 0.f, 0.f};

    for (int k0 = 0; k0 < Kd; k0 += 64) {
        __syncthreads();
#pragma unroll
        for (int i = 0; i < 4; i++) {
            int tc = tid + i * 256;          // chunk 0..1023
            int r = tc >> 3, cl = tc & 7;
            int cg = cl ^ (r & 7);
            gload16(A + (size_t)(rowA0 + r) * Kd + k0 + cg * 8, &As[tc * 8]);
            gload16(B + (size_t)(rowB0 + r) * Kd + k0 + cg * 8, &Bs[tc * 8]);
        }
        __syncthreads();

#pragma unroll
        for (int ks = 0; ks < 2; ks++) {
            const int kc = (ks * 4 + l4) ^ sw;
            short8 af[4], bf[4];
#pragma unroll
            for (int i = 0; i < 4; i++)
                af[i] = *(const short8*)&As[(wr + i*16 + l15)*64 + kc*8];
#pragma unroll
            for (int j = 0; j < 4; j++)
                bf[j] = *(const short8*)&Bs[(wc + j*16 + l15)*64 + kc*8];
#pragma unroll
            for (int i = 0; i < 4; i++)
#pragma unroll
                for (int j = 0; j < 4; j++)
                    R.acc[i][j] = __builtin_amdgcn_mfma_f32_16x16x32_bf16(
                        af[i], bf[j], R.acc[i][j], 0, 0, 0);
        }
    }
}

// ---------------------------------------------------------------------------
// Fused QKV projection + RMSNorm + RoPE.
// bx<32 -> Q head bx, bx<40 -> K head bx-32: one block's C-tile is 128 s-rows
// x the FULL 128-d head vector, so norm (reduce over d) and RoPE (pair
// d <-> d^64) are block-local:
//   1. per-row sum(x^2) over this wave's 64 cols via shfl_xor(l15) -> 1 KB
//      LDS exchange across the wave pair (wc=0 <-> wc=64) -> rsqrt.
//   2. write x_hat = x*rinv*w[d] (bf16) into the dead As/Bs LDS (32 KB tile,
//      col XOR-swizzled by row -> <=2-way bank conflicts).
//   3. partner read x_hat[col^64] + cos/sin tables -> RoPE -> store.
// RMS now computed from fp32 acc (reference computes it pre-bf16 too).
// bx>=40 -> V written TRANSPOSED as VT[kvh][d][s] (no norm/rope).
// ---------------------------------------------------------------------------
__global__ __launch_bounds__(256) void gemm_qkv(
    const unsigned short* __restrict__ A,
    const unsigned short* __restrict__ Wq, const unsigned short* __restrict__ Wk,
    const unsigned short* __restrict__ Wv,
    const float* __restrict__ ct, const float* __restrict__ st,
    const float* __restrict__ qw, const float* __restrict__ kw,
    unsigned short* __restrict__ Qo, unsigned short* __restrict__ Ko,
    unsigned short* __restrict__ VTo)
{
    __shared__ unsigned short Sh[128*128];  // As|Bs in K-loop; x_hat tile after
    __shared__ float part[4][4][4][4];      // [w][i][l4][r] row-ssq partials
    unsigned short* As = Sh;
    unsigned short* Bs = Sh + 128*64;

    const int bx = blockIdx.x;              // 0..47
    const unsigned short* B;
    if (bx < 32)      B = Wq + (size_t)bx*128*HID;
    else if (bx < 40) B = Wk + (size_t)(bx-32)*128*HID;
    else              B = Wv + (size_t)(bx-40)*128*HID;

    const int tid = threadIdx.x;
    const int lane = tid & 63, w = tid >> 6;
    const int l15 = lane & 15, l4 = lane >> 4;
    const int wr = (w >> 1) * 64, wc = (w & 1) * 64;
    GemmRegs R;
    gemm_core(A, B, HID, As, Bs, R, blockIdx.y * 128, 0, tid);

    if (bx < 40) {
        const float* W = (bx < 32) ? qw : kw;
        unsigned short* C; int ldc, cb;
        if (bx < 32) { C = Qo; ldc = QDIM;  cb = bx*128; }
        else         { C = Ko; ldc = KVDIM; cb = (bx-32)*128; }

        // 1. per-row sum of squares over this wave's 64 cols
        float ssq[4][4];
#pragma unroll
        for (int i = 0; i < 4; i++)
#pragma unroll
            for (int r = 0; r < 4; r++) {
                float s = 0.f;
#pragma unroll
                for (int j = 0; j < 4; j++)
                    s += R.acc[i][j][r] * R.acc[i][j][r];
#pragma unroll
                for (int off = 1; off < 16; off <<= 1)
                    s += __shfl_xor(s, off, 64);
                ssq[i][r] = s;
            }
        if (l15 == 0) {
#pragma unroll
            for (int i = 0; i < 4; i++)
#pragma unroll
                for (int r = 0; r < 4; r++)
                    part[w][i][l4][r] = ssq[i][r];
        }
        __syncthreads();    // partials visible; all MFMA reads of Sh done

        // 2. rinv + write x_hat tile (bf16, swizzled)
#pragma unroll
        for (int i = 0; i < 4; i++)
#pragma unroll
            for (int r = 0; r < 4; r++) {
                float rv = rsqrtf((ssq[i][r] + part[w ^ 1][i][l4][r])
                                  * (1.0f/128.0f) + 1e-6f);
                int row_l = wr + i*16 + l4*4 + r;
                int sx = (row_l & 7) << 3;
#pragma unroll
                for (int j = 0; j < 4; j++) {
                    int col = wc + j*16 + l15;
                    float v = R.acc[i][j][r] * rv * W[col];
                    R.acc[i][j][r] = v;      // keep fp32 for own-value path
                    Sh[row_l*128 + (col ^ sx)] = f2bf(v);
                }
            }
        __syncthreads();

        // 3. RoPE: out = x*cos + (col<64 ? -1 : +1) * x[col^64] * sin
        const float sgn = (wc == 0) ? -1.0f : 1.0f;
#pragma unroll
        for (int i = 0; i < 4; i++)
#pragma unroll
            for (int j = 0; j < 4; j++)
#pragma unroll
                for (int r = 0; r < 4; r++) {
                    int row_l = wr + i*16 + l4*4 + r;
                    int srow  = blockIdx.y*128 + row_l;
                    int col   = wc + j*16 + l15;
                    int sx    = (row_l & 7) << 3;
                    float xo  = bf2f(Sh[row_l*128 + ((col ^ 64) ^ sx)]);
                    float c   = ct[srow*HD + col];
                    float sn  = st[srow*HD + col];
                    float o   = R.acc[i][j][r] * c + sgn * xo * sn;
                    C[(size_t)srow * ldc + cb + col] = f2bf(o);
                }
    } else {
        const int cbase = (bx - 40) * 128;
#pragma unroll
        for (int i = 0; i < 4; i++)
#pragma unroll
            for (int j = 0; j < 4; j++) {
                int col  = cbase + wc + j*16 + l15;            // v-dim 0..1023
                int row0 = blockIdx.y*128 + wr + i*16 + l4*4;  // s
                int kvhh = col >> 7, d = col & 127;
                unsigned short* p = VTo + (size_t)kvhh*HD*S_LEN + (size_t)d*S_LEN + row0;
                uint2 pk;
                pk.x = pk2bf(R.acc[i][j][0], R.acc[i][j][1]);
                pk.y = pk2bf(R.acc[i][j][2], R.acc[i][j][3]);
                *(uint2*)p = pk;
            }
    }
}

// ---------------------------------------------------------------------------
// Out-projection GEMM: 64x128 tiles -> grid (20,32) = 640 blocks (2.5/CU
// schedule util ~83% vs 320-block 62.5%). 4 waves as 2x2 of 32x64.
// (Round-0 proven form; dbuf variant measured net-negative in round 4.)
// ---------------------------------------------------------------------------
__global__ __launch_bounds__(256) void gemm_out(
    const unsigned short* __restrict__ A, const unsigned short* __restrict__ B,
    float* __restrict__ C, int N, int Kd)
{
    __shared__ unsigned short As[64*64];    // 8 KB
    __shared__ unsigned short Bs[128*64];   // 16 KB
    const int tid = threadIdx.x;
    const int lane = tid & 63, w = tid >> 6;
    const int l15 = lane & 15, l4 = lane >> 4;
    const int wr = (w >> 1) * 32, wc = (w & 1) * 64;
    const int rowA0 = blockIdx.y * 64, rowB0 = blockIdx.x * 128;
    const int sw = l15 & 7;

    f32x4 acc[2][4];
#pragma unroll
    for (int i = 0; i < 2; i++)
#pragma unroll
        for (int j = 0; j < 4; j++) acc[i][j] = (f32x4){0.f, 0.f, 0.f, 0.f};

    for (int k0 = 0; k0 < Kd; k0 += 64) {
        __syncthreads();
#pragma unroll
        for (int i = 0; i < 2; i++) {       // A: 512 chunks
            int tc = tid + i * 256;
            int r = tc >> 3, cl = tc & 7;
            int cg = cl ^ (r & 7);
            gload16(A + (size_t)(rowA0 + r) * Kd + k0 + cg * 8, &As[tc * 8]);
        }
#pragma unroll
        for (int i = 0; i < 4; i++) {       // B: 1024 chunks
            int tc = tid + i * 256;
            int r = tc >> 3, cl = tc & 7;
            int cg = cl ^ (r & 7);
            gload16(B + (size_t)(rowB0 + r) * Kd + k0 + cg * 8, &Bs[tc * 8]);
        }
        __syncthreads();

#pragma unroll
        for (int ks = 0; ks < 2; ks++) {
            const int kc = (ks * 4 + l4) ^ sw;
            short8 af[2], bf[4];
#pragma unroll
            for (int i = 0; i < 2; i++)
                af[i] = *(const short8*)&As[(wr + i*16 + l15)*64 + kc*8];
#pragma unroll
            for (int j = 0; j < 4; j++)
                bf[j] = *(const short8*)&Bs[(wc + j*16 + l15)*64 + kc*8];
#pragma unroll
            for (int i = 0; i < 2; i++)
#pragma unroll
                for (int j = 0; j < 4; j++)
                    acc[i][j] = __builtin_amdgcn_mfma_f32_16x16x32_bf16(
                        af[i], bf[j], acc[i][j], 0, 0, 0);
        }
    }

#pragma unroll
    for (int i = 0; i < 2; i++)
#pragma unroll
        for (int j = 0; j < 4; j++) {
            int row0 = rowA0 + wr + i*16 + l4*4;
            int col  = rowB0 + wc + j*16 + l15;
#pragma unroll
            for (int r = 0; r < 4; r++)
                C[(size_t)(row0 + r) * N + col] = acc[i][j][r];
        }
}

// ---------------------------------------------------------------------------
// Flash attention v5: bf16 MFMA, causal, GQA, fixed-max softmax.
// (Round-0 proven form; dbuf variant measured net-negative in round 4.)
// Balanced pairing grid: block pb does Q-tiles (31-pb) then pb -> every
// block = exactly 33 tile-units; 512 blocks, all co-resident.
// ---------------------------------------------------------------------------
__global__ __launch_bounds__(256, 3) void flash_mfma(
    const unsigned short* __restrict__ Q, const unsigned short* __restrict__ K,
    const unsigned short* __restrict__ VT, unsigned short* __restrict__ O)
{
    const int pb = blockIdx.x;               // 0..15
    const int h = blockIdx.y, kvh = h >> 2;
    const int tid = threadIdx.x;
    const int w = tid >> 6, lane = tid & 63;
    const int l15 = lane & 15, l4 = lane >> 4;

    __shared__ unsigned short Ks[64*128];    // swizzled chunks, 16 KB
    __shared__ unsigned short Vt[128*64];    // V^T [d][kv], swizzled, 16 KB
    __shared__ unsigned short Ps[4*16*72];   // per-wave P strips [q][kv], 9 KB
    __shared__ float Lw[4][16];              // per-wave row sums

    const float scale2 = 0.08838834764831845f * 1.4426950408889634f;
    const float M2 = 17.3f;                  // fixed max: |score| <= 11.32
    unsigned short* Pw = &Ps[w * 16 * 72];
    const unsigned short* VTh = VT + (size_t)kvh * HD * S_LEN;

#pragma unroll 1
    for (int phase = 0; phase < 2; phase++) {
        const int qt = phase ? pb : (31 - pb);
        const int q0 = qt * 64;

        // Q fragments: B-operand layout = lane l15 -> q-row, l4*8 -> k
        short8 qa[4];
        {
            const unsigned short* qg = Q + (size_t)(q0 + w*16 + l15) * QDIM + h * HD;
#pragma unroll
            for (int ka = 0; ka < 4; ka++)
                qa[ka] = *(const short8*)(qg + ka*32 + l4*8);
        }

        const f32x4 zero = {0.f, 0.f, 0.f, 0.f};
        f32x4 accO[8];
#pragma unroll
        for (int j = 0; j < 8; j++) accO[j] = zero;
        float lsum = 0.f;

        for (int t = 0; t <= qt; t++) {
            const int c0 = t * 64;
            __syncthreads();
            {   // stage K tile [64 kv][128 k]: 1024 chunks, XOR swizzle
#pragma unroll
                for (int i = 0; i < 4; i++) {
                    int tc = tid + i * 256;
                    int r = tc >> 4, cl = tc & 15;
                    int cg = cl ^ (r & 7);
                    gload16(K + (size_t)(c0 + r) * KVDIM + kvh * HD + cg * 8,
                            &Ks[tc * 8]);
                }
            }
            {   // stage V^T tile [128 d][64 kv]: 1024 chunks, XOR swizzle
#pragma unroll
                for (int i = 0; i < 4; i++) {
                    int tc = tid + i * 256;
                    int r = tc >> 3, cl = tc & 7;
                    int cg = cl ^ (r & 7);
                    gload16(VTh + (size_t)r * S_LEN + c0 + cg * 8, &Vt[tc * 8]);
                }
            }
            __syncthreads();

            // ---- S^T = K Q^T : C rows = kv (mt*16+l4*4+r), cols = q (l15)
            f32x4 sc[4];
#pragma unroll
            for (int mt = 0; mt < 4; mt++) sc[mt] = zero;
#pragma unroll
            for (int ka = 0; ka < 4; ka++) {
#pragma unroll
                for (int mt = 0; mt < 4; mt++) {
                    int row = mt*16 + l15;
                    int cs = (ka*4 + l4) ^ (row & 7);
                    short8 kb = *(const short8*)&Ks[row*128 + cs*8];
                    sc[mt] = __builtin_amdgcn_mfma_f32_16x16x32_bf16(kb, qa[ka], sc[mt], 0, 0, 0);
                }
            }

            // ---- fixed-max softmax + causal mask + packed P store ----
            const int qglob = q0 + w*16 + l15;
            const bool diag = (t == qt);
#pragma unroll
            for (int mt = 0; mt < 4; mt++) {
                float pv[4];
#pragma unroll
                for (int r = 0; r < 4; r++) {
                    int kvg = c0 + mt*16 + l4*4 + r;
                    float e = __builtin_amdgcn_exp2f(fmaf(sc[mt][r], scale2, -M2));
                    pv[r] = (!diag || kvg <= qglob) ? e : 0.f;
                    lsum += pv[r];
                }
                uint2 pk;
                pk.x = pk2bf(pv[0], pv[1]);
                pk.y = pk2bf(pv[2], pv[3]);
                *(uint2*)&Pw[l15*72 + mt*16 + l4*4] = pk;   // P[q][kv]
            }

            // ---- PV: accO[dt] += P x V^T (A=P, B=V^T) ----
#pragma unroll
            for (int ks = 0; ks < 2; ks++) {
                short8 pf = *(const short8*)&Pw[l15*72 + ks*32 + l4*8];
                const int cs = (ks*4 + l4) ^ (l15 & 7);   // (dt*16+l15)&7 == l15&7
#pragma unroll
                for (int dt = 0; dt < 8; dt++) {
                    short8 vf = *(const short8*)&Vt[(dt*16 + l15)*64 + cs*8];
                    accO[dt] = __builtin_amdgcn_mfma_f32_16x16x32_bf16(pf, vf, accO[dt], 0, 0, 0);
                }
            }
        }

        // ---- finalize l: reduce over the 4 l4 groups ----
        lsum += __shfl_xor(lsum, 16, 64);
        lsum += __shfl_xor(lsum, 32, 64);
        if (l4 == 0) Lw[w][l15] = lsum;      // wave-lockstep LDS exchange
        f32x4 linv;
#pragma unroll
        for (int r = 0; r < 4; r++) linv[r] = 1.0f / Lw[w][l4*4 + r];

        // epilogue: O rows = q (l4*4+r), cols = d (dt*16+l15)
#pragma unroll
        for (int dt = 0; dt < 8; dt++)
#pragma unroll
            for (int r = 0; r < 4; r++) {
                int row_l = w*16 + l4*4 + r;
                O[(size_t)(q0 + row_l) * QDIM + h*HD + dt*16 + l15] =
                    f2bf(accO[dt][r] * linv[r]);
            }
    }
}

// ---------------------------------------------------------------------------
extern "C" void kernel_launch(void* const* d_in, const int* in_sizes, int n_in,
                              void* d_out, int out_size, void* d_ws, size_t ws_size,
                              hipStream_t stream)
{
    const float* hs   = (const float*)d_in[0];
    const float* cosb = (const float*)d_in[1];
    const float* sinb = (const float*)d_in[2];
    const float* Wq   = (const float*)d_in[3];
    const float* Wk   = (const float*)d_in[4];
    const float* Wv   = (const float*)d_in[5];
    const float* Wo   = (const float*)d_in[6];
    const float* qw   = (const float*)d_in[7];
    const float* kw   = (const float*)d_in[8];
    float* out = (float*)d_out;

    // Workspace layout (peak 79.7 MB):
    //   hsB 0..10.49M | WqB 10.49..31.46M | WkB 31.46..36.70M | WvB 36.70..41.94M
    //   KB 41.94..46.14M, VT 46.14..50.33M  (inside WoB slot; dead after flash)
    //   WoB 41.94..62.91M (converted AFTER flash, overwrites KB/VT)
    //   QB 62.91..79.69M | CB 18.87..35.65M (aliases WqB tail + WkB; dead after
    //   QKV GEMM, written by flash, read by out-proj)
    char* ws = (char*)d_ws;
    unsigned short* hsB = (unsigned short*)(ws);
    unsigned short* WqB = (unsigned short*)(ws + 10485760);
    unsigned short* WkB = (unsigned short*)(ws + 31457280);
    unsigned short* WvB = (unsigned short*)(ws + 36700160);
    unsigned short* KB  = (unsigned short*)(ws + 41943040);
    unsigned short* VT  = (unsigned short*)(ws + 46137344);
    unsigned short* WoB = (unsigned short*)(ws + 41943040);
    unsigned short* QB  = (unsigned short*)(ws + 62914560);
    unsigned short* CB  = (unsigned short*)(ws + 18874368);

    // converts for hs + Wq + Wk + Wv (one launch)
    {
        int n4 = N4_HS + N4_WQ + 2 * N4_WKV;
        cvt4<<<(n4+255)/256, 256, 0, stream>>>(hs, Wq, Wk, Wv, hsB, WqB, WkB, WvB);
    }

    // fused QKV projection + RMSNorm + RoPE (Q,K final bf16; V transposed)
    gemm_qkv<<<dim3(48, S_LEN/128), 256, 0, stream>>>(
        hsB, WqB, WkB, WvB, cosb, sinb, qw, kw, QB, KB, VT);

    // attention: 16 balanced pair-blocks x 32 heads (512 uniform blocks)
    flash_mfma<<<dim3(16, NH), 256, 0, stream>>>(QB, KB, VT, CB);

    // convert Wo now (KB/VT dead; WoB overwrites their slot)
    cvt_f32_bf16<<<(HID*QDIM/4+255)/256, 256, 0, stream>>>(Wo, WoB, HID*QDIM/4);

    // output projection (fp32 out), 64x128 tiles -> 640 blocks
    gemm_out<<<dim3(HID/128, S_LEN/64), 256, 0, stream>>>(CB, WoB, out, HID, QDIM);
}

// Round 6
// 385.256 us; speedup vs baseline: 1.0265x; 1.0265x over previous
//
#include <hip/hip_runtime.h>
#include <hip/hip_bf16.h>

// Problem constants
#define S_LEN   2048
#define HID     2560
#define NH      32
#define NKV     8
#define HD      128
#define QDIM    (NH*HD)    // 4096
#define KVDIM   (NKV*HD)   // 1024

typedef __attribute__((ext_vector_type(8))) short short8;   // 8 bf16 (4 VGPRs)
typedef __attribute__((ext_vector_type(4))) float f32x4;    // MFMA C/D frag

__device__ __forceinline__ unsigned short f2bf(float f) {
    unsigned u = __float_as_uint(f);
    u += 0x7fffu + ((u >> 16) & 1u);        // round-to-nearest-even
    return (unsigned short)(u >> 16);
}
__device__ __forceinline__ float bf2f(unsigned short s) {
    return __uint_as_float(((unsigned)s) << 16);
}
// packed f32x2 -> bf16x2 (v_cvt_pk_bf16_f32 on gfx950)
__device__ __forceinline__ unsigned pk2bf(float a, float b) {
    __hip_bfloat162 h = __float22bfloat162_rn(make_float2(a, b));
    union { __hip_bfloat162 h; unsigned u; } c; c.h = h; return c.u;
}
__device__ __forceinline__ void gload16(const void* g, void* l) {
    __builtin_amdgcn_global_load_lds(
        (const __attribute__((address_space(1))) unsigned int*)g,
        (__attribute__((address_space(3))) unsigned int*)l, 16, 0, 0);
}

// ---------------------------------------------------------------------------
// Fused fp32 -> bf16 converts: hs, Wq, Wk, Wv in one segmented launch.
// ---------------------------------------------------------------------------
#define N4_HS  (S_LEN*HID/4)        // 1310720
#define N4_WQ  (QDIM*HID/4)         // 2621440
#define N4_WKV (KVDIM*HID/4)        // 655360
__global__ __launch_bounds__(256) void cvt4(
    const float* __restrict__ hs, const float* __restrict__ Wq,
    const float* __restrict__ Wk, const float* __restrict__ Wv,
    unsigned short* __restrict__ hsB, unsigned short* __restrict__ WqB,
    unsigned short* __restrict__ WkB, unsigned short* __restrict__ WvB)
{
    int i = blockIdx.x * 256 + threadIdx.x;
    const float* s; unsigned short* d;
    if (i < N4_HS)                          { s = hs; d = hsB; }
    else if (i < N4_HS + N4_WQ)             { i -= N4_HS; s = Wq; d = WqB; }
    else if (i < N4_HS + N4_WQ + N4_WKV)    { i -= N4_HS + N4_WQ; s = Wk; d = WkB; }
    else                                    { i -= N4_HS + N4_WQ + N4_WKV; s = Wv; d = WvB; }
    float4 v = ((const float4*)s)[i];
    uint2 o;
    o.x = pk2bf(v.x, v.y); o.y = pk2bf(v.z, v.w);
    ((uint2*)d)[i] = o;
}

__global__ __launch_bounds__(256) void cvt_f32_bf16(
    const float* __restrict__ s, unsigned short* __restrict__ d, int n4)
{
    int i = blockIdx.x * 256 + threadIdx.x;
    if (i >= n4) return;
    float4 v = ((const float4*)s)[i];
    uint2 o;
    o.x = pk2bf(v.x, v.y); o.y = pk2bf(v.z, v.w);
    ((uint2*)d)[i] = o;
}

// ---------------------------------------------------------------------------
// BK=64 GEMM core (128x128): 256 threads, 4 waves (2x2 of 64x64).
// XOR swizzle on the GLOBAL chunk; fragment reads apply the same XOR.
// (Round-0 proven form, 76 µs. Rewrites measured: 256² 8-phase 86-100 µs,
//  epilogue-fused norm/rope 122 µs — both reverted; see journal.)
// ---------------------------------------------------------------------------
struct GemmRegs {
    f32x4 acc[4][4];
};
__device__ __forceinline__ void gemm_core(
    const unsigned short* A, const unsigned short* B, int Kd,
    unsigned short* As, unsigned short* Bs, GemmRegs& R,
    int rowA0, int rowB0, int tid)
{
    const int lane = tid & 63;
    const int l15 = lane & 15, l4 = lane >> 4;
    const int w = tid >> 6;
    const int wr = (w >> 1) * 64, wc = (w & 1) * 64;
    const int sw = l15 & 7;                 // read-side XOR swizzle

#pragma unroll
    for (int i = 0; i < 4; i++)
#pragma unroll
        for (int j = 0; j < 4; j++)
            R.acc[i][j] = (f32x4){0.f, 0.f, 0.f, 0.f};

    for (int k0 = 0; k0 < Kd; k0 += 64) {
        __syncthreads();
#pragma unroll
        for (int i = 0; i < 4; i++) {
            int tc = tid + i * 256;          // chunk 0..1023
            int r = tc >> 3, cl = tc & 7;
            int cg = cl ^ (r & 7);
            gload16(A + (size_t)(rowA0 + r) * Kd + k0 + cg * 8, &As[tc * 8]);
            gload16(B + (size_t)(rowB0 + r) * Kd + k0 + cg * 8, &Bs[tc * 8]);
        }
        __syncthreads();

#pragma unroll
        for (int ks = 0; ks < 2; ks++) {
            const int kc = (ks * 4 + l4) ^ sw;
            short8 af[4], bf[4];
#pragma unroll
            for (int i = 0; i < 4; i++)
                af[i] = *(const short8*)&As[(wr + i*16 + l15)*64 + kc*8];
#pragma unroll
            for (int j = 0; j < 4; j++)
                bf[j] = *(const short8*)&Bs[(wc + j*16 + l15)*64 + kc*8];
#pragma unroll
            for (int i = 0; i < 4; i++)
#pragma unroll
                for (int j = 0; j < 4; j++)
                    R.acc[i][j] = __builtin_amdgcn_mfma_f32_16x16x32_bf16(
                        af[i], bf[j], R.acc[i][j], 0, 0, 0);
        }
    }
}

// Fused QKV projection. bx<32 -> Q, <40 -> K, else V written TRANSPOSED as
// VT[kvh][d][s] (acc regs r=0..3 are consecutive s -> packed uint2 stores).
__global__ __launch_bounds__(256) void gemm_qkv(
    const unsigned short* __restrict__ A,
    const unsigned short* __restrict__ Wq, const unsigned short* __restrict__ Wk,
    const unsigned short* __restrict__ Wv,
    unsigned short* __restrict__ Qo, unsigned short* __restrict__ Ko,
    unsigned short* __restrict__ VTo)
{
    __shared__ unsigned short As[128*64];
    __shared__ unsigned short Bs[128*64];
    const int bx = blockIdx.x;              // 0..47
    const unsigned short* B;
    if (bx < 32)      B = Wq + (size_t)bx*128*HID;
    else if (bx < 40) B = Wk + (size_t)(bx-32)*128*HID;
    else              B = Wv + (size_t)(bx-40)*128*HID;

    const int tid = threadIdx.x;
    const int lane = tid & 63, w = tid >> 6;
    const int l15 = lane & 15, l4 = lane >> 4;
    const int wr = (w >> 1) * 64, wc = (w & 1) * 64;
    GemmRegs R;
    gemm_core(A, B, HID, As, Bs, R, blockIdx.y * 128, 0, tid);

    if (bx < 40) {
        unsigned short* C; int ldc, cb;
        if (bx < 32) { C = Qo; ldc = QDIM;  cb = bx*128; }
        else         { C = Ko; ldc = KVDIM; cb = (bx-32)*128; }
#pragma unroll
        for (int i = 0; i < 4; i++)
#pragma unroll
            for (int j = 0; j < 4; j++) {
                int row0 = blockIdx.y*128 + wr + i*16 + l4*4;
                int col  = cb + wc + j*16 + l15;
#pragma unroll
                for (int r = 0; r < 4; r++)
                    C[(size_t)(row0 + r) * ldc + col] = f2bf(R.acc[i][j][r]);
            }
    } else {
        const int cbase = (bx - 40) * 128;
#pragma unroll
        for (int i = 0; i < 4; i++)
#pragma unroll
            for (int j = 0; j < 4; j++) {
                int col  = cbase + wc + j*16 + l15;            // v-dim 0..1023
                int row0 = blockIdx.y*128 + wr + i*16 + l4*4;  // s
                int kvhh = col >> 7, d = col & 127;
                unsigned short* p = VTo + (size_t)kvhh*HD*S_LEN + (size_t)d*S_LEN + row0;
                uint2 pk;
                pk.x = pk2bf(R.acc[i][j][0], R.acc[i][j][1]);
                pk.y = pk2bf(R.acc[i][j][2], R.acc[i][j][3]);
                *(uint2*)p = pk;
            }
    }
}

// ---------------------------------------------------------------------------
// Out-projection GEMM: 64x128 tiles -> grid (20,32) = 640 blocks (2.5/CU
// schedule util ~83% vs 320-block 62.5%). 4 waves as 2x2 of 32x64.
// (Round-0 proven form; dbuf variant measured net-negative in round 4.)
// ---------------------------------------------------------------------------
__global__ __launch_bounds__(256) void gemm_out(
    const unsigned short* __restrict__ A, const unsigned short* __restrict__ B,
    float* __restrict__ C, int N, int Kd)
{
    __shared__ unsigned short As[64*64];    // 8 KB
    __shared__ unsigned short Bs[128*64];   // 16 KB
    const int tid = threadIdx.x;
    const int lane = tid & 63, w = tid >> 6;
    const int l15 = lane & 15, l4 = lane >> 4;
    const int wr = (w >> 1) * 32, wc = (w & 1) * 64;
    const int rowA0 = blockIdx.y * 64, rowB0 = blockIdx.x * 128;
    const int sw = l15 & 7;

    f32x4 acc[2][4];
#pragma unroll
    for (int i = 0; i < 2; i++)
#pragma unroll
        for (int j = 0; j < 4; j++) acc[i][j] = (f32x4){0.f, 0.f, 0.f, 0.f};

    for (int k0 = 0; k0 < Kd; k0 += 64) {
        __syncthreads();
#pragma unroll
        for (int i = 0; i < 2; i++) {       // A: 512 chunks
            int tc = tid + i * 256;
            int r = tc >> 3, cl = tc & 7;
            int cg = cl ^ (r & 7);
            gload16(A + (size_t)(rowA0 + r) * Kd + k0 + cg * 8, &As[tc * 8]);
        }
#pragma unroll
        for (int i = 0; i < 4; i++) {       // B: 1024 chunks
            int tc = tid + i * 256;
            int r = tc >> 3, cl = tc & 7;
            int cg = cl ^ (r & 7);
            gload16(B + (size_t)(rowB0 + r) * Kd + k0 + cg * 8, &Bs[tc * 8]);
        }
        __syncthreads();

#pragma unroll
        for (int ks = 0; ks < 2; ks++) {
            const int kc = (ks * 4 + l4) ^ sw;
            short8 af[2], bf[4];
#pragma unroll
            for (int i = 0; i < 2; i++)
                af[i] = *(const short8*)&As[(wr + i*16 + l15)*64 + kc*8];
#pragma unroll
            for (int j = 0; j < 4; j++)
                bf[j] = *(const short8*)&Bs[(wc + j*16 + l15)*64 + kc*8];
#pragma unroll
            for (int i = 0; i < 2; i++)
#pragma unroll
                for (int j = 0; j < 4; j++)
                    acc[i][j] = __builtin_amdgcn_mfma_f32_16x16x32_bf16(
                        af[i], bf[j], acc[i][j], 0, 0, 0);
        }
    }

#pragma unroll
    for (int i = 0; i < 2; i++)
#pragma unroll
        for (int j = 0; j < 4; j++) {
            int row0 = rowA0 + wr + i*16 + l4*4;
            int col  = rowB0 + wc + j*16 + l15;
#pragma unroll
            for (int r = 0; r < 4; r++)
                C[(size_t)(row0 + r) * N + col] = acc[i][j][r];
        }
}

// ---------------------------------------------------------------------------
// RMSNorm (per 128-d head vector) + RoPE, in place on bf16.
// MERGED: Q section (wid < S*NH) and K section in ONE launch (saves a
// dispatch; NH=32, NKV=8 are powers of two -> shift/mask indexing).
// Math byte-identical to the two-launch version.
// ---------------------------------------------------------------------------
__global__ __launch_bounds__(256) void rmsnorm_rope_all(
    unsigned short* __restrict__ Qx, unsigned short* __restrict__ Kx,
    const float* __restrict__ qw, const float* __restrict__ kw,
    const float* __restrict__ ct, const float* __restrict__ st)
{
    int wid  = (blockIdx.x * blockDim.x + threadIdx.x) >> 6;  // 0..81919
    int lane = threadIdx.x & 63;
    unsigned short* x; const float* w; int s;
    if (wid < S_LEN * NH) {
        int h = wid & (NH - 1); s = wid >> 5;
        x = Qx + (size_t)s * QDIM + h * HD; w = qw;
    } else {
        wid -= S_LEN * NH;
        int h = wid & (NKV - 1); s = wid >> 3;
        x = Kx + (size_t)s * KVDIM + h * HD; w = kw;
    }

    float x1 = bf2f(x[lane]);
    float x2 = bf2f(x[lane + 64]);
    float ss = x1*x1 + x2*x2;
#pragma unroll
    for (int off = 32; off > 0; off >>= 1) ss += __shfl_xor(ss, off, 64);
    float r = rsqrtf(ss * (1.0f/128.0f) + 1e-6f);
    float n1 = x1 * r * w[lane];
    float n2 = x2 * r * w[lane + 64];
    float c1 = ct[s*HD + lane],      s1 = st[s*HD + lane];
    float c2 = ct[s*HD + lane + 64], s2 = st[s*HD + lane + 64];
    x[lane]      = f2bf(n1*c1 - n2*s1);
    x[lane + 64] = f2bf(n2*c2 + n1*s2);
}

// ---------------------------------------------------------------------------
// Flash attention v5+T5: bf16 MFMA, causal, GQA, fixed-max softmax.
// Round-0 structure (single-buffered staging; dbuf measured net-negative).
// ONLY change: s_setprio(1) around the QK^T and PV MFMA clusters (T5 —
// 512 independent blocks at 3/CU put waves at different phases, the regime
// where setprio pays on attn [m191]; null/negative on lockstep GEMM [m190]).
// ---------------------------------------------------------------------------
__global__ __launch_bounds__(256, 3) void flash_mfma(
    const unsigned short* __restrict__ Q, const unsigned short* __restrict__ K,
    const unsigned short* __restrict__ VT, unsigned short* __restrict__ O)
{
    const int pb = blockIdx.x;               // 0..15
    const int h = blockIdx.y, kvh = h >> 2;
    const int tid = threadIdx.x;
    const int w = tid >> 6, lane = tid & 63;
    const int l15 = lane & 15, l4 = lane >> 4;

    __shared__ unsigned short Ks[64*128];    // swizzled chunks, 16 KB
    __shared__ unsigned short Vt[128*64];    // V^T [d][kv], swizzled, 16 KB
    __shared__ unsigned short Ps[4*16*72];   // per-wave P strips [q][kv], 9 KB
    __shared__ float Lw[4][16];              // per-wave row sums

    const float scale2 = 0.08838834764831845f * 1.4426950408889634f;
    const float M2 = 17.3f;                  // fixed max: |score| <= 11.32
    unsigned short* Pw = &Ps[w * 16 * 72];
    const unsigned short* VTh = VT + (size_t)kvh * HD * S_LEN;

#pragma unroll 1
    for (int phase = 0; phase < 2; phase++) {
        const int qt = phase ? pb : (31 - pb);
        const int q0 = qt * 64;

        // Q fragments: B-operand layout = lane l15 -> q-row, l4*8 -> k
        short8 qa[4];
        {
            const unsigned short* qg = Q + (size_t)(q0 + w*16 + l15) * QDIM + h * HD;
#pragma unroll
            for (int ka = 0; ka < 4; ka++)
                qa[ka] = *(const short8*)(qg + ka*32 + l4*8);
        }

        const f32x4 zero = {0.f, 0.f, 0.f, 0.f};
        f32x4 accO[8];
#pragma unroll
        for (int j = 0; j < 8; j++) accO[j] = zero;
        float lsum = 0.f;

        for (int t = 0; t <= qt; t++) {
            const int c0 = t * 64;
            __syncthreads();
            {   // stage K tile [64 kv][128 k]: 1024 chunks, XOR swizzle
#pragma unroll
                for (int i = 0; i < 4; i++) {
                    int tc = tid + i * 256;
                    int r = tc >> 4, cl = tc & 15;
                    int cg = cl ^ (r & 7);
                    gload16(K + (size_t)(c0 + r) * KVDIM + kvh * HD + cg * 8,
                            &Ks[tc * 8]);
                }
            }
            {   // stage V^T tile [128 d][64 kv]: 1024 chunks, XOR swizzle
#pragma unroll
                for (int i = 0; i < 4; i++) {
                    int tc = tid + i * 256;
                    int r = tc >> 3, cl = tc & 7;
                    int cg = cl ^ (r & 7);
                    gload16(VTh + (size_t)r * S_LEN + c0 + cg * 8, &Vt[tc * 8]);
                }
            }
            __syncthreads();

            // ---- S^T = K Q^T : C rows = kv (mt*16+l4*4+r), cols = q (l15)
            f32x4 sc[4];
#pragma unroll
            for (int mt = 0; mt < 4; mt++) sc[mt] = zero;
            __builtin_amdgcn_s_setprio(1);
#pragma unroll
            for (int ka = 0; ka < 4; ka++) {
#pragma unroll
                for (int mt = 0; mt < 4; mt++) {
                    int row = mt*16 + l15;
                    int cs = (ka*4 + l4) ^ (row & 7);
                    short8 kb = *(const short8*)&Ks[row*128 + cs*8];
                    sc[mt] = __builtin_amdgcn_mfma_f32_16x16x32_bf16(kb, qa[ka], sc[mt], 0, 0, 0);
                }
            }
            __builtin_amdgcn_s_setprio(0);

            // ---- fixed-max softmax + causal mask + packed P store ----
            const int qglob = q0 + w*16 + l15;
            const bool diag = (t == qt);
#pragma unroll
            for (int mt = 0; mt < 4; mt++) {
                float pv[4];
#pragma unroll
                for (int r = 0; r < 4; r++) {
                    int kvg = c0 + mt*16 + l4*4 + r;
                    float e = __builtin_amdgcn_exp2f(fmaf(sc[mt][r], scale2, -M2));
                    pv[r] = (!diag || kvg <= qglob) ? e : 0.f;
                    lsum += pv[r];
                }
                uint2 pk;
                pk.x = pk2bf(pv[0], pv[1]);
                pk.y = pk2bf(pv[2], pv[3]);
                *(uint2*)&Pw[l15*72 + mt*16 + l4*4] = pk;   // P[q][kv]
            }

            // ---- PV: accO[dt] += P x V^T (A=P, B=V^T) ----
            __builtin_amdgcn_s_setprio(1);
#pragma unroll
            for (int ks = 0; ks < 2; ks++) {
                short8 pf = *(const short8*)&Pw[l15*72 + ks*32 + l4*8];
                const int cs = (ks*4 + l4) ^ (l15 & 7);   // (dt*16+l15)&7 == l15&7
#pragma unroll
                for (int dt = 0; dt < 8; dt++) {
                    short8 vf = *(const short8*)&Vt[(dt*16 + l15)*64 + cs*8];
                    accO[dt] = __builtin_amdgcn_mfma_f32_16x16x32_bf16(pf, vf, accO[dt], 0, 0, 0);
                }
            }
            __builtin_amdgcn_s_setprio(0);
        }

        // ---- finalize l: reduce over the 4 l4 groups ----
        lsum += __shfl_xor(lsum, 16, 64);
        lsum += __shfl_xor(lsum, 32, 64);
        if (l4 == 0) Lw[w][l15] = lsum;      // wave-lockstep LDS exchange
        f32x4 linv;
#pragma unroll
        for (int r = 0; r < 4; r++) linv[r] = 1.0f / Lw[w][l4*4 + r];

        // epilogue: O rows = q (l4*4+r), cols = d (dt*16+l15)
#pragma unroll
        for (int dt = 0; dt < 8; dt++)
#pragma unroll
            for (int r = 0; r < 4; r++) {
                int row_l = w*16 + l4*4 + r;
                O[(size_t)(q0 + row_l) * QDIM + h*HD + dt*16 + l15] =
                    f2bf(accO[dt][r] * linv[r]);
            }
    }
}

// ---------------------------------------------------------------------------
extern "C" void kernel_launch(void* const* d_in, const int* in_sizes, int n_in,
                              void* d_out, int out_size, void* d_ws, size_t ws_size,
                              hipStream_t stream)
{
    const float* hs   = (const float*)d_in[0];
    const float* cosb = (const float*)d_in[1];
    const float* sinb = (const float*)d_in[2];
    const float* Wq   = (const float*)d_in[3];
    const float* Wk   = (const float*)d_in[4];
    const float* Wv   = (const float*)d_in[5];
    const float* Wo   = (const float*)d_in[6];
    const float* qw   = (const float*)d_in[7];
    const float* kw   = (const float*)d_in[8];
    float* out = (float*)d_out;

    // Workspace layout (peak 79.7 MB):
    //   hsB 0..10.49M | WqB 10.49..31.46M | WkB 31.46..36.70M | WvB 36.70..41.94M
    //   KB 41.94..46.14M, VT 46.14..50.33M  (inside WoB slot; dead after flash)
    //   WoB 41.94..62.91M (converted AFTER flash, overwrites KB/VT)
    //   QB 62.91..79.69M | CB 18.87..35.65M (aliases WqB tail + WkB; dead after
    //   QKV GEMM, written by flash, read by out-proj)
    char* ws = (char*)d_ws;
    unsigned short* hsB = (unsigned short*)(ws);
    unsigned short* WqB = (unsigned short*)(ws + 10485760);
    unsigned short* WkB = (unsigned short*)(ws + 31457280);
    unsigned short* WvB = (unsigned short*)(ws + 36700160);
    unsigned short* KB  = (unsigned short*)(ws + 41943040);
    unsigned short* VT  = (unsigned short*)(ws + 46137344);
    unsigned short* WoB = (unsigned short*)(ws + 41943040);
    unsigned short* QB  = (unsigned short*)(ws + 62914560);
    unsigned short* CB  = (unsigned short*)(ws + 18874368);

    // converts for hs + Wq + Wk + Wv (one launch)
    {
        int n4 = N4_HS + N4_WQ + 2 * N4_WKV;
        cvt4<<<(n4+255)/256, 256, 0, stream>>>(hs, Wq, Wk, Wv, hsB, WqB, WkB, WvB);
    }

    // fused QKV projection (Q,K row-major bf16; V transposed)
    gemm_qkv<<<dim3(48, S_LEN/128), 256, 0, stream>>>(hsB, WqB, WkB, WvB, QB, KB, VT);

    // norm + rope (in place, bf16; V needs none) — ONE merged launch
    rmsnorm_rope_all<<<S_LEN*(NH+NKV)/4, 256, 0, stream>>>(QB, KB, qw, kw, cosb, sinb);

    // attention: 16 balanced pair-blocks x 32 heads (512 uniform blocks)
    flash_mfma<<<dim3(16, NH), 256, 0, stream>>>(QB, KB, VT, CB);

    // convert Wo now (KB/VT dead; WoB overwrites their slot)
    cvt_f32_bf16<<<(HID*QDIM/4+255)/256, 256, 0, stream>>>(Wo, WoB, HID*QDIM/4);

    // output projection (fp32 out), 64x128 tiles -> 640 blocks
    gemm_out<<<dim3(HID/128, S_LEN/64), 256, 0, stream>>>(CB, WoB, out, HID, QDIM);
}

// Round 7
// 373.499 us; speedup vs baseline: 1.0588x; 1.0315x over previous
//
#include <hip/hip_runtime.h>
#include <hip/hip_bf16.h>

// Problem constants
#define S_LEN   2048
#define HID     2560
#define NH      32
#define NKV     8
#define HD      128
#define QDIM    (NH*HD)    // 4096
#define KVDIM   (NKV*HD)   // 1024

typedef __attribute__((ext_vector_type(8))) short short8;   // 8 bf16 (4 VGPRs)
typedef __attribute__((ext_vector_type(4))) float f32x4;    // MFMA C/D frag

__device__ __forceinline__ unsigned short f2bf(float f) {
    unsigned u = __float_as_uint(f);
    u += 0x7fffu + ((u >> 16) & 1u);        // round-to-nearest-even
    return (unsigned short)(u >> 16);
}
__device__ __forceinline__ float bf2f(unsigned short s) {
    return __uint_as_float(((unsigned)s) << 16);
}
// packed f32x2 -> bf16x2 (v_cvt_pk_bf16_f32 on gfx950)
__device__ __forceinline__ unsigned pk2bf(float a, float b) {
    __hip_bfloat162 h = __float22bfloat162_rn(make_float2(a, b));
    union { __hip_bfloat162 h; unsigned u; } c; c.h = h; return c.u;
}
__device__ __forceinline__ void gload16(const void* g, void* l) {
    __builtin_amdgcn_global_load_lds(
        (const __attribute__((address_space(1))) unsigned int*)g,
        (__attribute__((address_space(3))) unsigned int*)l, 16, 0, 0);
}

// ---------------------------------------------------------------------------
// Fused fp32 -> bf16 converts: hs, Wq, Wk, Wv in one segmented launch.
// ---------------------------------------------------------------------------
#define N4_HS  (S_LEN*HID/4)        // 1310720
#define N4_WQ  (QDIM*HID/4)         // 2621440
#define N4_WKV (KVDIM*HID/4)        // 655360
__global__ __launch_bounds__(256) void cvt4(
    const float* __restrict__ hs, const float* __restrict__ Wq,
    const float* __restrict__ Wk, const float* __restrict__ Wv,
    unsigned short* __restrict__ hsB, unsigned short* __restrict__ WqB,
    unsigned short* __restrict__ WkB, unsigned short* __restrict__ WvB)
{
    int i = blockIdx.x * 256 + threadIdx.x;
    const float* s; unsigned short* d;
    if (i < N4_HS)                          { s = hs; d = hsB; }
    else if (i < N4_HS + N4_WQ)             { i -= N4_HS; s = Wq; d = WqB; }
    else if (i < N4_HS + N4_WQ + N4_WKV)    { i -= N4_HS + N4_WQ; s = Wk; d = WkB; }
    else                                    { i -= N4_HS + N4_WQ + N4_WKV; s = Wv; d = WvB; }
    float4 v = ((const float4*)s)[i];
    uint2 o;
    o.x = pk2bf(v.x, v.y); o.y = pk2bf(v.z, v.w);
    ((uint2*)d)[i] = o;
}

__global__ __launch_bounds__(256) void cvt_f32_bf16(
    const float* __restrict__ s, unsigned short* __restrict__ d, int n4)
{
    int i = blockIdx.x * 256 + threadIdx.x;
    if (i >= n4) return;
    float4 v = ((const float4*)s)[i];
    uint2 o;
    o.x = pk2bf(v.x, v.y); o.y = pk2bf(v.z, v.w);
    ((uint2*)d)[i] = o;
}

// ---------------------------------------------------------------------------
// BK=64 GEMM core (128x128): 256 threads, 4 waves (2x2 of 64x64).
// XOR swizzle on the GLOBAL chunk; fragment reads apply the same XOR.
// (Round-0 proven form, 76 µs. Rewrites measured: 256² 8-phase 86-100 µs,
//  epilogue-fused norm/rope 122 µs — both reverted; see journal.)
// ---------------------------------------------------------------------------
struct GemmRegs {
    f32x4 acc[4][4];
};
__device__ __forceinline__ void gemm_core(
    const unsigned short* A, const unsigned short* B, int Kd,
    unsigned short* As, unsigned short* Bs, GemmRegs& R,
    int rowA0, int rowB0, int tid)
{
    const int lane = tid & 63;
    const int l15 = lane & 15, l4 = lane >> 4;
    const int w = tid >> 6;
    const int wr = (w >> 1) * 64, wc = (w & 1) * 64;
    const int sw = l15 & 7;                 // read-side XOR swizzle

#pragma unroll
    for (int i = 0; i < 4; i++)
#pragma unroll
        for (int j = 0; j < 4; j++)
            R.acc[i][j] = (f32x4){0.f, 0.f, 0.f, 0.f};

    for (int k0 = 0; k0 < Kd; k0 += 64) {
        __syncthreads();
#pragma unroll
        for (int i = 0; i < 4; i++) {
            int tc = tid + i * 256;          // chunk 0..1023
            int r = tc >> 3, cl = tc & 7;
            int cg = cl ^ (r & 7);
            gload16(A + (size_t)(rowA0 + r) * Kd + k0 + cg * 8, &As[tc * 8]);
            gload16(B + (size_t)(rowB0 + r) * Kd + k0 + cg * 8, &Bs[tc * 8]);
        }
        __syncthreads();

#pragma unroll
        for (int ks = 0; ks < 2; ks++) {
            const int kc = (ks * 4 + l4) ^ sw;
            short8 af[4], bf[4];
#pragma unroll
            for (int i = 0; i < 4; i++)
                af[i] = *(const short8*)&As[(wr + i*16 + l15)*64 + kc*8];
#pragma unroll
            for (int j = 0; j < 4; j++)
                bf[j] = *(const short8*)&Bs[(wc + j*16 + l15)*64 + kc*8];
#pragma unroll
            for (int i = 0; i < 4; i++)
#pragma unroll
                for (int j = 0; j < 4; j++)
                    R.acc[i][j] = __builtin_amdgcn_mfma_f32_16x16x32_bf16(
                        af[i], bf[j], R.acc[i][j], 0, 0, 0);
        }
    }
}

// Fused QKV projection. bx<32 -> Q, <40 -> K, else V written TRANSPOSED as
// VT[kvh][d][s] (acc regs r=0..3 are consecutive s -> packed uint2 stores).
__global__ __launch_bounds__(256) void gemm_qkv(
    const unsigned short* __restrict__ A,
    const unsigned short* __restrict__ Wq, const unsigned short* __restrict__ Wk,
    const unsigned short* __restrict__ Wv,
    unsigned short* __restrict__ Qo, unsigned short* __restrict__ Ko,
    unsigned short* __restrict__ VTo)
{
    __shared__ unsigned short As[128*64];
    __shared__ unsigned short Bs[128*64];
    const int bx = blockIdx.x;              // 0..47
    const unsigned short* B;
    if (bx < 32)      B = Wq + (size_t)bx*128*HID;
    else if (bx < 40) B = Wk + (size_t)(bx-32)*128*HID;
    else              B = Wv + (size_t)(bx-40)*128*HID;

    const int tid = threadIdx.x;
    const int lane = tid & 63, w = tid >> 6;
    const int l15 = lane & 15, l4 = lane >> 4;
    const int wr = (w >> 1) * 64, wc = (w & 1) * 64;
    GemmRegs R;
    gemm_core(A, B, HID, As, Bs, R, blockIdx.y * 128, 0, tid);

    if (bx < 40) {
        unsigned short* C; int ldc, cb;
        if (bx < 32) { C = Qo; ldc = QDIM;  cb = bx*128; }
        else         { C = Ko; ldc = KVDIM; cb = (bx-32)*128; }
#pragma unroll
        for (int i = 0; i < 4; i++)
#pragma unroll
            for (int j = 0; j < 4; j++) {
                int row0 = blockIdx.y*128 + wr + i*16 + l4*4;
                int col  = cb + wc + j*16 + l15;
#pragma unroll
                for (int r = 0; r < 4; r++)
                    C[(size_t)(row0 + r) * ldc + col] = f2bf(R.acc[i][j][r]);
            }
    } else {
        const int cbase = (bx - 40) * 128;
#pragma unroll
        for (int i = 0; i < 4; i++)
#pragma unroll
            for (int j = 0; j < 4; j++) {
                int col  = cbase + wc + j*16 + l15;            // v-dim 0..1023
                int row0 = blockIdx.y*128 + wr + i*16 + l4*4;  // s
                int kvhh = col >> 7, d = col & 127;
                unsigned short* p = VTo + (size_t)kvhh*HD*S_LEN + (size_t)d*S_LEN + row0;
                uint2 pk;
                pk.x = pk2bf(R.acc[i][j][0], R.acc[i][j][1]);
                pk.y = pk2bf(R.acc[i][j][2], R.acc[i][j][3]);
                *(uint2*)p = pk;
            }
    }
}

// ---------------------------------------------------------------------------
// Out-projection GEMM: 64x128 tiles -> grid (20,32) = 640 blocks (2.5/CU
// schedule util ~83% vs 320-block 62.5%). 4 waves as 2x2 of 32x64.
// (Round-0 proven form; dbuf variant measured net-negative in round 4.)
// ---------------------------------------------------------------------------
__global__ __launch_bounds__(256) void gemm_out(
    const unsigned short* __restrict__ A, const unsigned short* __restrict__ B,
    float* __restrict__ C, int N, int Kd)
{
    __shared__ unsigned short As[64*64];    // 8 KB
    __shared__ unsigned short Bs[128*64];   // 16 KB
    const int tid = threadIdx.x;
    const int lane = tid & 63, w = tid >> 6;
    const int l15 = lane & 15, l4 = lane >> 4;
    const int wr = (w >> 1) * 32, wc = (w & 1) * 64;
    const int rowA0 = blockIdx.y * 64, rowB0 = blockIdx.x * 128;
    const int sw = l15 & 7;

    f32x4 acc[2][4];
#pragma unroll
    for (int i = 0; i < 2; i++)
#pragma unroll
        for (int j = 0; j < 4; j++) acc[i][j] = (f32x4){0.f, 0.f, 0.f, 0.f};

    for (int k0 = 0; k0 < Kd; k0 += 64) {
        __syncthreads();
#pragma unroll
        for (int i = 0; i < 2; i++) {       // A: 512 chunks
            int tc = tid + i * 256;
            int r = tc >> 3, cl = tc & 7;
            int cg = cl ^ (r & 7);
            gload16(A + (size_t)(rowA0 + r) * Kd + k0 + cg * 8, &As[tc * 8]);
        }
#pragma unroll
        for (int i = 0; i < 4; i++) {       // B: 1024 chunks
            int tc = tid + i * 256;
            int r = tc >> 3, cl = tc & 7;
            int cg = cl ^ (r & 7);
            gload16(B + (size_t)(rowB0 + r) * Kd + k0 + cg * 8, &Bs[tc * 8]);
        }
        __syncthreads();

#pragma unroll
        for (int ks = 0; ks < 2; ks++) {
            const int kc = (ks * 4 + l4) ^ sw;
            short8 af[2], bf[4];
#pragma unroll
            for (int i = 0; i < 2; i++)
                af[i] = *(const short8*)&As[(wr + i*16 + l15)*64 + kc*8];
#pragma unroll
            for (int j = 0; j < 4; j++)
                bf[j] = *(const short8*)&Bs[(wc + j*16 + l15)*64 + kc*8];
#pragma unroll
            for (int i = 0; i < 2; i++)
#pragma unroll
                for (int j = 0; j < 4; j++)
                    acc[i][j] = __builtin_amdgcn_mfma_f32_16x16x32_bf16(
                        af[i], bf[j], acc[i][j], 0, 0, 0);
        }
    }

#pragma unroll
    for (int i = 0; i < 2; i++)
#pragma unroll
        for (int j = 0; j < 4; j++) {
            int row0 = rowA0 + wr + i*16 + l4*4;
            int col  = rowB0 + wc + j*16 + l15;
#pragma unroll
            for (int r = 0; r < 4; r++)
                C[(size_t)(row0 + r) * N + col] = acc[i][j][r];
        }
}

// ---------------------------------------------------------------------------
// RMSNorm (per 128-d head vector) + RoPE, in place on bf16.
// MERGED: Q section (wid < S*NH) and K section in ONE launch (saves a
// dispatch; NH=32, NKV=8 are powers of two -> shift/mask indexing).
// Math byte-identical to the two-launch version.
// ---------------------------------------------------------------------------
__global__ __launch_bounds__(256) void rmsnorm_rope_all(
    unsigned short* __restrict__ Qx, unsigned short* __restrict__ Kx,
    const float* __restrict__ qw, const float* __restrict__ kw,
    const float* __restrict__ ct, const float* __restrict__ st)
{
    int wid  = (blockIdx.x * blockDim.x + threadIdx.x) >> 6;  // 0..81919
    int lane = threadIdx.x & 63;
    unsigned short* x; const float* w; int s;
    if (wid < S_LEN * NH) {
        int h = wid & (NH - 1); s = wid >> 5;
        x = Qx + (size_t)s * QDIM + h * HD; w = qw;
    } else {
        wid -= S_LEN * NH;
        int h = wid & (NKV - 1); s = wid >> 3;
        x = Kx + (size_t)s * KVDIM + h * HD; w = kw;
    }

    float x1 = bf2f(x[lane]);
    float x2 = bf2f(x[lane + 64]);
    float ss = x1*x1 + x2*x2;
#pragma unroll
    for (int off = 32; off > 0; off >>= 1) ss += __shfl_xor(ss, off, 64);
    float r = rsqrtf(ss * (1.0f/128.0f) + 1e-6f);
    float n1 = x1 * r * w[lane];
    float n2 = x2 * r * w[lane + 64];
    float c1 = ct[s*HD + lane],      s1 = st[s*HD + lane];
    float c2 = ct[s*HD + lane + 64], s2 = st[s*HD + lane + 64];
    x[lane]      = f2bf(n1*c1 - n2*s1);
    x[lane + 64] = f2bf(n2*c2 + n1*s2);
}

// ---------------------------------------------------------------------------
// Flash attention v5 (round-0 body, NO setprio — measured −12 µs in R6) with
// GQA/XCD-locality grid: flat 512 blocks, decoded so bid%8 == kvh. The
// dispatcher round-robins linear block id across the 8 XCDs, so each XCD
// serves ONE kv-head group -> per-XCD K/V working set 1.05 MB (L2-resident)
// instead of 8.4 MB (> 4 MB L2). Pure index remap; math identical.
// Balanced pairing: block pb does Q-tiles (31-pb) then pb = 33 tile-units.
// ---------------------------------------------------------------------------
__global__ __launch_bounds__(256, 3) void flash_mfma(
    const unsigned short* __restrict__ Q, const unsigned short* __restrict__ K,
    const unsigned short* __restrict__ VT, unsigned short* __restrict__ O)
{
    const int bid = blockIdx.x;              // 0..511
    const int kvh = bid & 7;                 // XCD-locality: kvh == bid%8
    const int h   = kvh * 4 + ((bid >> 3) & 3);
    const int pb  = bid >> 5;                // 0..15
    const int tid = threadIdx.x;
    const int w = tid >> 6, lane = tid & 63;
    const int l15 = lane & 15, l4 = lane >> 4;

    __shared__ unsigned short Ks[64*128];    // swizzled chunks, 16 KB
    __shared__ unsigned short Vt[128*64];    // V^T [d][kv], swizzled, 16 KB
    __shared__ unsigned short Ps[4*16*72];   // per-wave P strips [q][kv], 9 KB
    __shared__ float Lw[4][16];              // per-wave row sums

    const float scale2 = 0.08838834764831845f * 1.4426950408889634f;
    const float M2 = 17.3f;                  // fixed max: |score| <= 11.32
    unsigned short* Pw = &Ps[w * 16 * 72];
    const unsigned short* VTh = VT + (size_t)kvh * HD * S_LEN;

#pragma unroll 1
    for (int phase = 0; phase < 2; phase++) {
        const int qt = phase ? pb : (31 - pb);
        const int q0 = qt * 64;

        // Q fragments: B-operand layout = lane l15 -> q-row, l4*8 -> k
        short8 qa[4];
        {
            const unsigned short* qg = Q + (size_t)(q0 + w*16 + l15) * QDIM + h * HD;
#pragma unroll
            for (int ka = 0; ka < 4; ka++)
                qa[ka] = *(const short8*)(qg + ka*32 + l4*8);
        }

        const f32x4 zero = {0.f, 0.f, 0.f, 0.f};
        f32x4 accO[8];
#pragma unroll
        for (int j = 0; j < 8; j++) accO[j] = zero;
        float lsum = 0.f;

        for (int t = 0; t <= qt; t++) {
            const int c0 = t * 64;
            __syncthreads();
            {   // stage K tile [64 kv][128 k]: 1024 chunks, XOR swizzle
#pragma unroll
                for (int i = 0; i < 4; i++) {
                    int tc = tid + i * 256;
                    int r = tc >> 4, cl = tc & 15;
                    int cg = cl ^ (r & 7);
                    gload16(K + (size_t)(c0 + r) * KVDIM + kvh * HD + cg * 8,
                            &Ks[tc * 8]);
                }
            }
            {   // stage V^T tile [128 d][64 kv]: 1024 chunks, XOR swizzle
#pragma unroll
                for (int i = 0; i < 4; i++) {
                    int tc = tid + i * 256;
                    int r = tc >> 3, cl = tc & 7;
                    int cg = cl ^ (r & 7);
                    gload16(VTh + (size_t)r * S_LEN + c0 + cg * 8, &Vt[tc * 8]);
                }
            }
            __syncthreads();

            // ---- S^T = K Q^T : C rows = kv (mt*16+l4*4+r), cols = q (l15)
            f32x4 sc[4];
#pragma unroll
            for (int mt = 0; mt < 4; mt++) sc[mt] = zero;
#pragma unroll
            for (int ka = 0; ka < 4; ka++) {
#pragma unroll
                for (int mt = 0; mt < 4; mt++) {
                    int row = mt*16 + l15;
                    int cs = (ka*4 + l4) ^ (row & 7);
                    short8 kb = *(const short8*)&Ks[row*128 + cs*8];
                    sc[mt] = __builtin_amdgcn_mfma_f32_16x16x32_bf16(kb, qa[ka], sc[mt], 0, 0, 0);
                }
            }

            // ---- fixed-max softmax + causal mask + packed P store ----
            const int qglob = q0 + w*16 + l15;
            const bool diag = (t == qt);
#pragma unroll
            for (int mt = 0; mt < 4; mt++) {
                float pv[4];
#pragma unroll
                for (int r = 0; r < 4; r++) {
                    int kvg = c0 + mt*16 + l4*4 + r;
                    float e = __builtin_amdgcn_exp2f(fmaf(sc[mt][r], scale2, -M2));
                    pv[r] = (!diag || kvg <= qglob) ? e : 0.f;
                    lsum += pv[r];
                }
                uint2 pk;
                pk.x = pk2bf(pv[0], pv[1]);
                pk.y = pk2bf(pv[2], pv[3]);
                *(uint2*)&Pw[l15*72 + mt*16 + l4*4] = pk;   // P[q][kv]
            }

            // ---- PV: accO[dt] += P x V^T (A=P, B=V^T) ----
#pragma unroll
            for (int ks = 0; ks < 2; ks++) {
                short8 pf = *(const short8*)&Pw[l15*72 + ks*32 + l4*8];
                const int cs = (ks*4 + l4) ^ (l15 & 7);   // (dt*16+l15)&7 == l15&7
#pragma unroll
                for (int dt = 0; dt < 8; dt++) {
                    short8 vf = *(const short8*)&Vt[(dt*16 + l15)*64 + cs*8];
                    accO[dt] = __builtin_amdgcn_mfma_f32_16x16x32_bf16(pf, vf, accO[dt], 0, 0, 0);
                }
            }
        }

        // ---- finalize l: reduce over the 4 l4 groups ----
        lsum += __shfl_xor(lsum, 16, 64);
        lsum += __shfl_xor(lsum, 32, 64);
        if (l4 == 0) Lw[w][l15] = lsum;      // wave-lockstep LDS exchange
        f32x4 linv;
#pragma unroll
        for (int r = 0; r < 4; r++) linv[r] = 1.0f / Lw[w][l4*4 + r];

        // epilogue: O rows = q (l4*4+r), cols = d (dt*16+l15)
#pragma unroll
        for (int dt = 0; dt < 8; dt++)
#pragma unroll
            for (int r = 0; r < 4; r++) {
                int row_l = w*16 + l4*4 + r;
                O[(size_t)(q0 + row_l) * QDIM + h*HD + dt*16 + l15] =
                    f2bf(accO[dt][r] * linv[r]);
            }
    }
}

// ---------------------------------------------------------------------------
extern "C" void kernel_launch(void* const* d_in, const int* in_sizes, int n_in,
                              void* d_out, int out_size, void* d_ws, size_t ws_size,
                              hipStream_t stream)
{
    const float* hs   = (const float*)d_in[0];
    const float* cosb = (const float*)d_in[1];
    const float* sinb = (const float*)d_in[2];
    const float* Wq   = (const float*)d_in[3];
    const float* Wk   = (const float*)d_in[4];
    const float* Wv   = (const float*)d_in[5];
    const float* Wo   = (const float*)d_in[6];
    const float* qw   = (const float*)d_in[7];
    const float* kw   = (const float*)d_in[8];
    float* out = (float*)d_out;

    // Workspace layout (peak 79.7 MB):
    //   hsB 0..10.49M | WqB 10.49..31.46M | WkB 31.46..36.70M | WvB 36.70..41.94M
    //   KB 41.94..46.14M, VT 46.14..50.33M  (inside WoB slot; dead after flash)
    //   WoB 41.94..62.91M (converted AFTER flash, overwrites KB/VT)
    //   QB 62.91..79.69M | CB 18.87..35.65M (aliases WqB tail + WkB; dead after
    //   QKV GEMM, written by flash, read by out-proj)
    char* ws = (char*)d_ws;
    unsigned short* hsB = (unsigned short*)(ws);
    unsigned short* WqB = (unsigned short*)(ws + 10485760);
    unsigned short* WkB = (unsigned short*)(ws + 31457280);
    unsigned short* WvB = (unsigned short*)(ws + 36700160);
    unsigned short* KB  = (unsigned short*)(ws + 41943040);
    unsigned short* VT  = (unsigned short*)(ws + 46137344);
    unsigned short* WoB = (unsigned short*)(ws + 41943040);
    unsigned short* QB  = (unsigned short*)(ws + 62914560);
    unsigned short* CB  = (unsigned short*)(ws + 18874368);

    // converts for hs + Wq + Wk + Wv (one launch)
    {
        int n4 = N4_HS + N4_WQ + 2 * N4_WKV;
        cvt4<<<(n4+255)/256, 256, 0, stream>>>(hs, Wq, Wk, Wv, hsB, WqB, WkB, WvB);
    }

    // fused QKV projection (Q,K row-major bf16; V transposed)
    gemm_qkv<<<dim3(48, S_LEN/128), 256, 0, stream>>>(hsB, WqB, WkB, WvB, QB, KB, VT);

    // norm + rope (in place, bf16; V needs none) — ONE merged launch
    rmsnorm_rope_all<<<S_LEN*(NH+NKV)/4, 256, 0, stream>>>(QB, KB, qw, kw, cosb, sinb);

    // attention: flat 512 blocks, kvh == bid%8 (XCD locality)
    flash_mfma<<<512, 256, 0, stream>>>(QB, KB, VT, CB);

    // convert Wo now (KB/VT dead; WoB overwrites their slot)
    cvt_f32_bf16<<<(HID*QDIM/4+255)/256, 256, 0, stream>>>(Wo, WoB, HID*QDIM/4);

    // output projection (fp32 out), 64x128 tiles -> 640 blocks
    gemm_out<<<dim3(HID/128, S_LEN/64), 256, 0, stream>>>(CB, WoB, out, HID, QDIM);
}

// Round 8
// 359.745 us; speedup vs baseline: 1.0993x; 1.0382x over previous
//
#include <hip/hip_runtime.h>
#include <hip/hip_bf16.h>

// Problem constants
#define S_LEN   2048
#define HID     2560
#define NH      32
#define NKV     8
#define HD      128
#define QDIM    (NH*HD)    // 4096
#define KVDIM   (NKV*HD)   // 1024

typedef __attribute__((ext_vector_type(8))) short short8;   // 8 bf16 (4 VGPRs)
typedef __attribute__((ext_vector_type(4))) float f32x4;    // MFMA C/D frag

__device__ __forceinline__ unsigned short f2bf(float f) {
    unsigned u = __float_as_uint(f);
    u += 0x7fffu + ((u >> 16) & 1u);        // round-to-nearest-even
    return (unsigned short)(u >> 16);
}
__device__ __forceinline__ float bf2f(unsigned short s) {
    return __uint_as_float(((unsigned)s) << 16);
}
// packed f32x2 -> bf16x2 (v_cvt_pk_bf16_f32 on gfx950)
__device__ __forceinline__ unsigned pk2bf(float a, float b) {
    __hip_bfloat162 h = __float22bfloat162_rn(make_float2(a, b));
    union { __hip_bfloat162 h; unsigned u; } c; c.h = h; return c.u;
}
__device__ __forceinline__ void gload16(const void* g, void* l) {
    __builtin_amdgcn_global_load_lds(
        (const __attribute__((address_space(1))) unsigned int*)g,
        (__attribute__((address_space(3))) unsigned int*)l, 16, 0, 0);
}

// ---------------------------------------------------------------------------
// Fused fp32 -> bf16 converts: hs, Wq, Wk, Wv in one segmented launch.
// ---------------------------------------------------------------------------
#define N4_HS  (S_LEN*HID/4)        // 1310720
#define N4_WQ  (QDIM*HID/4)         // 2621440
#define N4_WKV (KVDIM*HID/4)        // 655360
__global__ __launch_bounds__(256) void cvt4(
    const float* __restrict__ hs, const float* __restrict__ Wq,
    const float* __restrict__ Wk, const float* __restrict__ Wv,
    unsigned short* __restrict__ hsB, unsigned short* __restrict__ WqB,
    unsigned short* __restrict__ WkB, unsigned short* __restrict__ WvB)
{
    int i = blockIdx.x * 256 + threadIdx.x;
    const float* s; unsigned short* d;
    if (i < N4_HS)                          { s = hs; d = hsB; }
    else if (i < N4_HS + N4_WQ)             { i -= N4_HS; s = Wq; d = WqB; }
    else if (i < N4_HS + N4_WQ + N4_WKV)    { i -= N4_HS + N4_WQ; s = Wk; d = WkB; }
    else                                    { i -= N4_HS + N4_WQ + N4_WKV; s = Wv; d = WvB; }
    float4 v = ((const float4*)s)[i];
    uint2 o;
    o.x = pk2bf(v.x, v.y); o.y = pk2bf(v.z, v.w);
    ((uint2*)d)[i] = o;
}

__global__ __launch_bounds__(256) void cvt_f32_bf16(
    const float* __restrict__ s, unsigned short* __restrict__ d, int n4)
{
    int i = blockIdx.x * 256 + threadIdx.x;
    if (i >= n4) return;
    float4 v = ((const float4*)s)[i];
    uint2 o;
    o.x = pk2bf(v.x, v.y); o.y = pk2bf(v.z, v.w);
    ((uint2*)d)[i] = o;
}

// ---------------------------------------------------------------------------
// BK=64 GEMM core (128x128): 256 threads, 4 waves (2x2 of 64x64).
// XOR swizzle on the GLOBAL chunk; fragment reads apply the same XOR.
// (Round-0 proven form, 76 µs = ~95% of the m97-structure ceiling.)
// ---------------------------------------------------------------------------
struct GemmRegs {
    f32x4 acc[4][4];
};
__device__ __forceinline__ void gemm_core(
    const unsigned short* A, const unsigned short* B, int Kd,
    unsigned short* As, unsigned short* Bs, GemmRegs& R,
    int rowA0, int rowB0, int tid)
{
    const int lane = tid & 63;
    const int l15 = lane & 15, l4 = lane >> 4;
    const int w = tid >> 6;
    const int wr = (w >> 1) * 64, wc = (w & 1) * 64;
    const int sw = l15 & 7;                 // read-side XOR swizzle

#pragma unroll
    for (int i = 0; i < 4; i++)
#pragma unroll
        for (int j = 0; j < 4; j++)
            R.acc[i][j] = (f32x4){0.f, 0.f, 0.f, 0.f};

    for (int k0 = 0; k0 < Kd; k0 += 64) {
        __syncthreads();
#pragma unroll
        for (int i = 0; i < 4; i++) {
            int tc = tid + i * 256;          // chunk 0..1023
            int r = tc >> 3, cl = tc & 7;
            int cg = cl ^ (r & 7);
            gload16(A + (size_t)(rowA0 + r) * Kd + k0 + cg * 8, &As[tc * 8]);
            gload16(B + (size_t)(rowB0 + r) * Kd + k0 + cg * 8, &Bs[tc * 8]);
        }
        __syncthreads();

#pragma unroll
        for (int ks = 0; ks < 2; ks++) {
            const int kc = (ks * 4 + l4) ^ sw;
            short8 af[4], bf[4];
#pragma unroll
            for (int i = 0; i < 4; i++)
                af[i] = *(const short8*)&As[(wr + i*16 + l15)*64 + kc*8];
#pragma unroll
            for (int j = 0; j < 4; j++)
                bf[j] = *(const short8*)&Bs[(wc + j*16 + l15)*64 + kc*8];
#pragma unroll
            for (int i = 0; i < 4; i++)
#pragma unroll
                for (int j = 0; j < 4; j++)
                    R.acc[i][j] = __builtin_amdgcn_mfma_f32_16x16x32_bf16(
                        af[i], bf[j], R.acc[i][j], 0, 0, 0);
        }
    }
}

// Fused QKV projection. bx<32 -> Q, <40 -> K, else V written TRANSPOSED as
// VT[kvh][d][s] (acc regs r=0..3 are consecutive s -> packed uint2 stores).
__global__ __launch_bounds__(256) void gemm_qkv(
    const unsigned short* __restrict__ A,
    const unsigned short* __restrict__ Wq, const unsigned short* __restrict__ Wk,
    const unsigned short* __restrict__ Wv,
    unsigned short* __restrict__ Qo, unsigned short* __restrict__ Ko,
    unsigned short* __restrict__ VTo)
{
    __shared__ unsigned short As[128*64];
    __shared__ unsigned short Bs[128*64];
    const int bx = blockIdx.x;              // 0..47
    const unsigned short* B;
    if (bx < 32)      B = Wq + (size_t)bx*128*HID;
    else if (bx < 40) B = Wk + (size_t)(bx-32)*128*HID;
    else              B = Wv + (size_t)(bx-40)*128*HID;

    const int tid = threadIdx.x;
    const int lane = tid & 63, w = tid >> 6;
    const int l15 = lane & 15, l4 = lane >> 4;
    const int wr = (w >> 1) * 64, wc = (w & 1) * 64;
    GemmRegs R;
    gemm_core(A, B, HID, As, Bs, R, blockIdx.y * 128, 0, tid);

    if (bx < 40) {
        unsigned short* C; int ldc, cb;
        if (bx < 32) { C = Qo; ldc = QDIM;  cb = bx*128; }
        else         { C = Ko; ldc = KVDIM; cb = (bx-32)*128; }
#pragma unroll
        for (int i = 0; i < 4; i++)
#pragma unroll
            for (int j = 0; j < 4; j++) {
                int row0 = blockIdx.y*128 + wr + i*16 + l4*4;
                int col  = cb + wc + j*16 + l15;
#pragma unroll
                for (int r = 0; r < 4; r++)
                    C[(size_t)(row0 + r) * ldc + col] = f2bf(R.acc[i][j][r]);
            }
    } else {
        const int cbase = (bx - 40) * 128;
#pragma unroll
        for (int i = 0; i < 4; i++)
#pragma unroll
            for (int j = 0; j < 4; j++) {
                int col  = cbase + wc + j*16 + l15;            // v-dim 0..1023
                int row0 = blockIdx.y*128 + wr + i*16 + l4*4;  // s
                int kvhh = col >> 7, d = col & 127;
                unsigned short* p = VTo + (size_t)kvhh*HD*S_LEN + (size_t)d*S_LEN + row0;
                uint2 pk;
                pk.x = pk2bf(R.acc[i][j][0], R.acc[i][j][1]);
                pk.y = pk2bf(R.acc[i][j][2], R.acc[i][j][3]);
                *(uint2*)p = pk;
            }
    }
}

// ---------------------------------------------------------------------------
// Out-projection GEMM v2: 64x160 tiles -> grid (16,32) = 512 blocks = 2/CU
// EXACT (100% schedule util; the 640-block 64x128 form was 2.5/CU = 83% —
// half the CUs ran a 3rd round while the rest idled). 4 waves as 2x2 of
// 32x80 (5 j-fragments of 16). B staging = 160x8 = 1280 chunks = 5x256
// (uniform); LDS 8+20=28 KB. K-accumulation order per element unchanged.
// ---------------------------------------------------------------------------
__global__ __launch_bounds__(256) void gemm_out(
    const unsigned short* __restrict__ A, const unsigned short* __restrict__ B,
    float* __restrict__ C, int N, int Kd)
{
    __shared__ unsigned short As[64*64];    // 8 KB
    __shared__ unsigned short Bs[160*64];   // 20 KB
    const int tid = threadIdx.x;
    const int lane = tid & 63, w = tid >> 6;
    const int l15 = lane & 15, l4 = lane >> 4;
    const int wr = (w >> 1) * 32, wc = (w & 1) * 80;
    const int rowA0 = blockIdx.y * 64, rowB0 = blockIdx.x * 160;
    const int sw = l15 & 7;

    f32x4 acc[2][5];
#pragma unroll
    for (int i = 0; i < 2; i++)
#pragma unroll
        for (int j = 0; j < 5; j++) acc[i][j] = (f32x4){0.f, 0.f, 0.f, 0.f};

    for (int k0 = 0; k0 < Kd; k0 += 64) {
        __syncthreads();
#pragma unroll
        for (int i = 0; i < 2; i++) {       // A: 512 chunks
            int tc = tid + i * 256;
            int r = tc >> 3, cl = tc & 7;
            int cg = cl ^ (r & 7);
            gload16(A + (size_t)(rowA0 + r) * Kd + k0 + cg * 8, &As[tc * 8]);
        }
#pragma unroll
        for (int i = 0; i < 5; i++) {       // B: 1280 chunks
            int tc = tid + i * 256;
            int r = tc >> 3, cl = tc & 7;
            int cg = cl ^ (r & 7);
            gload16(B + (size_t)(rowB0 + r) * Kd + k0 + cg * 8, &Bs[tc * 8]);
        }
        __syncthreads();

#pragma unroll
        for (int ks = 0; ks < 2; ks++) {
            const int kc = (ks * 4 + l4) ^ sw;
            short8 af[2], bf[5];
#pragma unroll
            for (int i = 0; i < 2; i++)
                af[i] = *(const short8*)&As[(wr + i*16 + l15)*64 + kc*8];
#pragma unroll
            for (int j = 0; j < 5; j++)
                bf[j] = *(const short8*)&Bs[(wc + j*16 + l15)*64 + kc*8];
#pragma unroll
            for (int i = 0; i < 2; i++)
#pragma unroll
                for (int j = 0; j < 5; j++)
                    acc[i][j] = __builtin_amdgcn_mfma_f32_16x16x32_bf16(
                        af[i], bf[j], acc[i][j], 0, 0, 0);
        }
    }

#pragma unroll
    for (int i = 0; i < 2; i++)
#pragma unroll
        for (int j = 0; j < 5; j++) {
            int row0 = rowA0 + wr + i*16 + l4*4;
            int col  = rowB0 + wc + j*16 + l15;
#pragma unroll
            for (int r = 0; r < 4; r++)
                C[(size_t)(row0 + r) * N + col] = acc[i][j][r];
        }
}

// ---------------------------------------------------------------------------
// RMSNorm (per 128-d head vector) + RoPE, in place on bf16.
// MERGED: Q section (wid < S*NH) and K section in ONE launch.
// ---------------------------------------------------------------------------
__global__ __launch_bounds__(256) void rmsnorm_rope_all(
    unsigned short* __restrict__ Qx, unsigned short* __restrict__ Kx,
    const float* __restrict__ qw, const float* __restrict__ kw,
    const float* __restrict__ ct, const float* __restrict__ st)
{
    int wid  = (blockIdx.x * blockDim.x + threadIdx.x) >> 6;  // 0..81919
    int lane = threadIdx.x & 63;
    unsigned short* x; const float* w; int s;
    if (wid < S_LEN * NH) {
        int h = wid & (NH - 1); s = wid >> 5;
        x = Qx + (size_t)s * QDIM + h * HD; w = qw;
    } else {
        wid -= S_LEN * NH;
        int h = wid & (NKV - 1); s = wid >> 3;
        x = Kx + (size_t)s * KVDIM + h * HD; w = kw;
    }

    float x1 = bf2f(x[lane]);
    float x2 = bf2f(x[lane + 64]);
    float ss = x1*x1 + x2*x2;
#pragma unroll
    for (int off = 32; off > 0; off >>= 1) ss += __shfl_xor(ss, off, 64);
    float r = rsqrtf(ss * (1.0f/128.0f) + 1e-6f);
    float n1 = x1 * r * w[lane];
    float n2 = x2 * r * w[lane + 64];
    float c1 = ct[s*HD + lane],      s1 = st[s*HD + lane];
    float c2 = ct[s*HD + lane + 64], s2 = st[s*HD + lane + 64];
    x[lane]      = f2bf(n1*c1 - n2*s1);
    x[lane + 64] = f2bf(n2*c2 + n1*s2);
}

// ---------------------------------------------------------------------------
// Flash attention v5 (round-0 body; setprio and dbuf variants measured
// net-negative, XCD swizzle neutral-kept). Flat 512 blocks, kvh == bid%8.
// Balanced pairing: block pb does Q-tiles (31-pb) then pb = 33 tile-units.
// ---------------------------------------------------------------------------
__global__ __launch_bounds__(256, 3) void flash_mfma(
    const unsigned short* __restrict__ Q, const unsigned short* __restrict__ K,
    const unsigned short* __restrict__ VT, unsigned short* __restrict__ O)
{
    const int bid = blockIdx.x;              // 0..511
    const int kvh = bid & 7;                 // XCD-locality: kvh == bid%8
    const int h   = kvh * 4 + ((bid >> 3) & 3);
    const int pb  = bid >> 5;                // 0..15
    const int tid = threadIdx.x;
    const int w = tid >> 6, lane = tid & 63;
    const int l15 = lane & 15, l4 = lane >> 4;

    __shared__ unsigned short Ks[64*128];    // swizzled chunks, 16 KB
    __shared__ unsigned short Vt[128*64];    // V^T [d][kv], swizzled, 16 KB
    __shared__ unsigned short Ps[4*16*72];   // per-wave P strips [q][kv], 9 KB
    __shared__ float Lw[4][16];              // per-wave row sums

    const float scale2 = 0.08838834764831845f * 1.4426950408889634f;
    const float M2 = 17.3f;                  // fixed max: |score| <= 11.32
    unsigned short* Pw = &Ps[w * 16 * 72];
    const unsigned short* VTh = VT + (size_t)kvh * HD * S_LEN;

#pragma unroll 1
    for (int phase = 0; phase < 2; phase++) {
        const int qt = phase ? pb : (31 - pb);
        const int q0 = qt * 64;

        // Q fragments: B-operand layout = lane l15 -> q-row, l4*8 -> k
        short8 qa[4];
        {
            const unsigned short* qg = Q + (size_t)(q0 + w*16 + l15) * QDIM + h * HD;
#pragma unroll
            for (int ka = 0; ka < 4; ka++)
                qa[ka] = *(const short8*)(qg + ka*32 + l4*8);
        }

        const f32x4 zero = {0.f, 0.f, 0.f, 0.f};
        f32x4 accO[8];
#pragma unroll
        for (int j = 0; j < 8; j++) accO[j] = zero;
        float lsum = 0.f;

        for (int t = 0; t <= qt; t++) {
            const int c0 = t * 64;
            __syncthreads();
            {   // stage K tile [64 kv][128 k]: 1024 chunks, XOR swizzle
#pragma unroll
                for (int i = 0; i < 4; i++) {
                    int tc = tid + i * 256;
                    int r = tc >> 4, cl = tc & 15;
                    int cg = cl ^ (r & 7);
                    gload16(K + (size_t)(c0 + r) * KVDIM + kvh * HD + cg * 8,
                            &Ks[tc * 8]);
                }
            }
            {   // stage V^T tile [128 d][64 kv]: 1024 chunks, XOR swizzle
#pragma unroll
                for (int i = 0; i < 4; i++) {
                    int tc = tid + i * 256;
                    int r = tc >> 3, cl = tc & 7;
                    int cg = cl ^ (r & 7);
                    gload16(VTh + (size_t)r * S_LEN + c0 + cg * 8, &Vt[tc * 8]);
                }
            }
            __syncthreads();

            // ---- S^T = K Q^T : C rows = kv (mt*16+l4*4+r), cols = q (l15)
            f32x4 sc[4];
#pragma unroll
            for (int mt = 0; mt < 4; mt++) sc[mt] = zero;
#pragma unroll
            for (int ka = 0; ka < 4; ka++) {
#pragma unroll
                for (int mt = 0; mt < 4; mt++) {
                    int row = mt*16 + l15;
                    int cs = (ka*4 + l4) ^ (row & 7);
                    short8 kb = *(const short8*)&Ks[row*128 + cs*8];
                    sc[mt] = __builtin_amdgcn_mfma_f32_16x16x32_bf16(kb, qa[ka], sc[mt], 0, 0, 0);
                }
            }

            // ---- fixed-max softmax + causal mask + packed P store ----
            const int qglob = q0 + w*16 + l15;
            const bool diag = (t == qt);
#pragma unroll
            for (int mt = 0; mt < 4; mt++) {
                float pv[4];
#pragma unroll
                for (int r = 0; r < 4; r++) {
                    int kvg = c0 + mt*16 + l4*4 + r;
                    float e = __builtin_amdgcn_exp2f(fmaf(sc[mt][r], scale2, -M2));
                    pv[r] = (!diag || kvg <= qglob) ? e : 0.f;
                    lsum += pv[r];
                }
                uint2 pk;
                pk.x = pk2bf(pv[0], pv[1]);
                pk.y = pk2bf(pv[2], pv[3]);
                *(uint2*)&Pw[l15*72 + mt*16 + l4*4] = pk;   // P[q][kv]
            }

            // ---- PV: accO[dt] += P x V^T (A=P, B=V^T) ----
#pragma unroll
            for (int ks = 0; ks < 2; ks++) {
                short8 pf = *(const short8*)&Pw[l15*72 + ks*32 + l4*8];
                const int cs = (ks*4 + l4) ^ (l15 & 7);   // (dt*16+l15)&7 == l15&7
#pragma unroll
                for (int dt = 0; dt < 8; dt++) {
                    short8 vf = *(const short8*)&Vt[(dt*16 + l15)*64 + cs*8];
                    accO[dt] = __builtin_amdgcn_mfma_f32_16x16x32_bf16(pf, vf, accO[dt], 0, 0, 0);
                }
            }
        }

        // ---- finalize l: reduce over the 4 l4 groups ----
        lsum += __shfl_xor(lsum, 16, 64);
        lsum += __shfl_xor(lsum, 32, 64);
        if (l4 == 0) Lw[w][l15] = lsum;      // wave-lockstep LDS exchange
        f32x4 linv;
#pragma unroll
        for (int r = 0; r < 4; r++) linv[r] = 1.0f / Lw[w][l4*4 + r];

        // epilogue: O rows = q (l4*4+r), cols = d (dt*16+l15)
#pragma unroll
        for (int dt = 0; dt < 8; dt++)
#pragma unroll
            for (int r = 0; r < 4; r++) {
                int row_l = w*16 + l4*4 + r;
                O[(size_t)(q0 + row_l) * QDIM + h*HD + dt*16 + l15] =
                    f2bf(accO[dt][r] * linv[r]);
            }
    }
}

// ---------------------------------------------------------------------------
extern "C" void kernel_launch(void* const* d_in, const int* in_sizes, int n_in,
                              void* d_out, int out_size, void* d_ws, size_t ws_size,
                              hipStream_t stream)
{
    const float* hs   = (const float*)d_in[0];
    const float* cosb = (const float*)d_in[1];
    const float* sinb = (const float*)d_in[2];
    const float* Wq   = (const float*)d_in[3];
    const float* Wk   = (const float*)d_in[4];
    const float* Wv   = (const float*)d_in[5];
    const float* Wo   = (const float*)d_in[6];
    const float* qw   = (const float*)d_in[7];
    const float* kw   = (const float*)d_in[8];
    float* out = (float*)d_out;

    // Workspace layout (peak 79.7 MB):
    //   hsB 0..10.49M | WqB 10.49..31.46M | WkB 31.46..36.70M | WvB 36.70..41.94M
    //   KB 41.94..46.14M, VT 46.14..50.33M  (inside WoB slot; dead after flash)
    //   WoB 41.94..62.91M (converted AFTER flash, overwrites KB/VT)
    //   QB 62.91..79.69M | CB 18.87..35.65M (aliases WqB tail + WkB; dead after
    //   QKV GEMM, written by flash, read by out-proj)
    char* ws = (char*)d_ws;
    unsigned short* hsB = (unsigned short*)(ws);
    unsigned short* WqB = (unsigned short*)(ws + 10485760);
    unsigned short* WkB = (unsigned short*)(ws + 31457280);
    unsigned short* WvB = (unsigned short*)(ws + 36700160);
    unsigned short* KB  = (unsigned short*)(ws + 41943040);
    unsigned short* VT  = (unsigned short*)(ws + 46137344);
    unsigned short* WoB = (unsigned short*)(ws + 41943040);
    unsigned short* QB  = (unsigned short*)(ws + 62914560);
    unsigned short* CB  = (unsigned short*)(ws + 18874368);

    // converts for hs + Wq + Wk + Wv (one launch)
    {
        int n4 = N4_HS + N4_WQ + 2 * N4_WKV;
        cvt4<<<(n4+255)/256, 256, 0, stream>>>(hs, Wq, Wk, Wv, hsB, WqB, WkB, WvB);
    }

    // fused QKV projection (Q,K row-major bf16; V transposed)
    gemm_qkv<<<dim3(48, S_LEN/128), 256, 0, stream>>>(hsB, WqB, WkB, WvB, QB, KB, VT);

    // norm + rope (in place, bf16; V needs none) — ONE merged launch
    rmsnorm_rope_all<<<S_LEN*(NH+NKV)/4, 256, 0, stream>>>(QB, KB, qw, kw, cosb, sinb);

    // attention: flat 512 blocks, kvh == bid%8 (XCD locality)
    flash_mfma<<<512, 256, 0, stream>>>(QB, KB, VT, CB);

    // convert Wo now (KB/VT dead; WoB overwrites their slot)
    cvt_f32_bf16<<<(HID*QDIM/4+255)/256, 256, 0, stream>>>(Wo, WoB, HID*QDIM/4);

    // output projection (fp32 out), 64x160 tiles -> 512 blocks = 2/CU exact
    gemm_out<<<dim3(HID/160, S_LEN/64), 256, 0, stream>>>(CB, WoB, out, HID, QDIM);
}